// Round 8
// baseline (968.046 us; speedup 1.0000x reference)
//
#include <hip/hip_runtime.h>
#include <hip/hip_bf16.h>
#include <math.h>

#define V     10000
#define EMB   512
#define H     1024
#define H3    3072
#define SEQ   64
#define NPAD  10048   // 157*64, padded N for score partials

typedef __attribute__((ext_vector_type(8))) unsigned short us8;
typedef __attribute__((ext_vector_type(8))) unsigned u32x8;

__device__ __forceinline__ float sigmoidf_(float x) { return 1.0f / (1.0f + expf(-x)); }
__device__ __forceinline__ float lof(unsigned u) { return __uint_as_float(u << 16); }
__device__ __forceinline__ float hif(unsigned u) { return __uint_as_float(u & 0xffff0000u); }
__device__ __forceinline__ unsigned short f2bf_rne(float f) {
    unsigned u = __float_as_uint(f);
    unsigned r = u + 0x7FFF + ((u >> 16) & 1);
    return (unsigned short)(r >> 16);
}

// ---------------- init: h ping-pong buffers + barrier counters ----------------
__global__ void init_h_kernel(const float* __restrict__ enc_state,
                              float* __restrict__ h0buf, float* __restrict__ h1buf,
                              int* __restrict__ bar) {
    int i = blockIdx.x * blockDim.x + threadIdx.x;
    if (i < H)            h0buf[i] = enc_state[i];
    else if (i < 2 * H)   h1buf[H + (i - H)] = enc_state[i];
    if (i < 1024) bar[i] = 0;
}

// ---------------- embedding gather ----------------
__global__ void embed_kernel(const int* __restrict__ cs, const int* __restrict__ sos,
                             const int* __restrict__ tgt, const float* __restrict__ emb,
                             float* __restrict__ e_enc, float* __restrict__ e_dec) {
    int t = blockIdx.x;  // 0..127
    int id;
    float* dst;
    if (t < SEQ) { id = cs[t]; dst = e_enc + (size_t)t * EMB; }
    else         { int td = t - SEQ; id = (td == 0) ? sos[0] : tgt[td - 1]; dst = e_dec + (size_t)td * EMB; }
    const float4* src4 = (const float4*)(emb + (size_t)id * EMB);
    float4* dst4 = (float4*)dst;
    dst4[threadIdx.x] = src4[threadIdx.x];
}

// ---------------- gi0 as tiled GEMM, batched over {enc,dec}: out = e @ W.T + b ----------------
__global__ __launch_bounds__(256) void gi_gemm_kernel(const float* __restrict__ Ae, const float* __restrict__ We,
                                                      const float* __restrict__ be, float* __restrict__ oe,
                                                      const float* __restrict__ Ad, const float* __restrict__ Wd,
                                                      const float* __restrict__ bd, float* __restrict__ od) {
    __shared__ float As[64][64 + 1];
    __shared__ float Bs[64][64 + 1];
    const float* A = blockIdx.y ? Ad : Ae;
    const float* W = blockIdx.y ? Wd : We;
    const float* bias = blockIdx.y ? bd : be;
    float* out = blockIdx.y ? od : oe;
    int n0 = blockIdx.x * 64;
    int tid = threadIdx.x;
    int tn = tid & 15, tm = tid >> 4;
    float acc[4][4] = {};
    for (int k0 = 0; k0 < EMB; k0 += 64) {
        for (int i = tid; i < 64 * 16; i += 256) {
            int m = i >> 4, kq = i & 15;
            float4 v = *(const float4*)(A + (size_t)m * EMB + k0 + kq * 4);
            As[kq * 4 + 0][m] = v.x; As[kq * 4 + 1][m] = v.y;
            As[kq * 4 + 2][m] = v.z; As[kq * 4 + 3][m] = v.w;
        }
        for (int i = tid; i < 64 * 16; i += 256) {
            int n = i >> 4, kq = i & 15;
            float4 v = *(const float4*)(W + (size_t)(n0 + n) * EMB + k0 + kq * 4);
            Bs[kq * 4 + 0][n] = v.x; Bs[kq * 4 + 1][n] = v.y;
            Bs[kq * 4 + 2][n] = v.z; Bs[kq * 4 + 3][n] = v.w;
        }
        __syncthreads();
        #pragma unroll 8
        for (int k = 0; k < 64; ++k) {
            float a[4], b[4];
            #pragma unroll
            for (int i = 0; i < 4; ++i) a[i] = As[k][tm * 4 + i];
            #pragma unroll
            for (int j = 0; j < 4; ++j) b[j] = Bs[k][tn * 4 + j];
            #pragma unroll
            for (int i = 0; i < 4; ++i)
                #pragma unroll
                for (int j = 0; j < 4; ++j) acc[i][j] += a[i] * b[j];
        }
        __syncthreads();
    }
    #pragma unroll
    for (int i = 0; i < 4; ++i) {
        int m = tm * 4 + i;
        #pragma unroll
        for (int j = 0; j < 4; ++j) {
            int r = n0 + tn * 4 + j;
            out[(size_t)m * H3 + r] = acc[i][j] + bias[r];
        }
    }
}

// ================= persistent recurrence kernel (v5: short RT chain) =================
// 128 blocks x 1024 threads (16 waves). Blocks 0..63 = A (layer0): wave w -> j = bid*16+w,
// 3 gate rows (24 packed VGPRs). Blocks 64..127 = B (layer1): wave w -> j = (bid-64)*16+w,
// ALL 6 gate rows in-wave (48 packed VGPRs) -> wave-local finalize, no LDS sred pass.
// h exchange via agent-scope relaxed atomics (no threadfence). Barrier: 16 groups x 8
// blocks -> root -> 16 replicated flags.
struct PArgs {
    const float *encWhh0, *encWih1, *encWhh1;
    const float *decWhh0, *decWih1, *decWhh1;
    const float *gi_enc0, *gi_dec0;
    const float *enc_bhh0, *dec_bhh0;
    const float *enc_bih1, *enc_bhh1, *dec_bih1, *dec_bhh1;
    float *h0buf, *h1buf, *states;
    int *bar;   // [32]=root, [64+g*16]=16 group counters, [512+g*16]=16 release flags
};

__device__ __forceinline__ void loadw3(const float* __restrict__ m, int j, int lane,
                                       u32x8& w0, u32x8& w1, u32x8& w2) {
    size_t b0 = (size_t)j * H + lane;
    size_t b1 = (size_t)(H + j) * H + lane;
    size_t b2 = (size_t)(2 * H + j) * H + lane;
    #pragma unroll
    for (int q = 0; q < 8; ++q) {
        w0[q] = (unsigned)f2bf_rne(m[b0 + 128 * q]) | ((unsigned)f2bf_rne(m[b0 + 128 * q + 64]) << 16);
        w1[q] = (unsigned)f2bf_rne(m[b1 + 128 * q]) | ((unsigned)f2bf_rne(m[b1 + 128 * q + 64]) << 16);
        w2[q] = (unsigned)f2bf_rne(m[b2 + 128 * q]) | ((unsigned)f2bf_rne(m[b2 + 128 * q + 64]) << 16);
    }
}

__global__ __launch_bounds__(1024, 4) void persist_kernel(PArgs a) {
    __shared__ __align__(16) float xh0[H];
    __shared__ __align__(16) float xh1[H];
    const int tid = threadIdx.x;
    const int w = tid >> 6, lane = tid & 63;
    const int bid = blockIdx.x;
    const bool isA = (bid < 64);
    const int j = (isA ? bid : (bid - 64)) * 16 + w;

    u32x8 w0, w1, w2, w3, w4, w5;   // A: w0..2 (Whh0). B: w0..2 = Wih1, w3..5 = Whh1
    if (isA) {
        loadw3(a.encWhh0, j, lane, w0, w1, w2);
    } else {
        loadw3(a.encWih1, j, lane, w0, w1, w2);
        loadw3(a.encWhh1, j, lane, w3, w4, w5);
    }

    // per-wave lane0 biases
    float b0 = 0.f, b1 = 0.f, b2 = 0.f, b3 = 0.f, b4 = 0.f, b5 = 0.f;
    if (lane == 0) {
        if (isA) { b0 = a.enc_bhh0[j]; b1 = a.enc_bhh0[H + j]; b2 = a.enc_bhh0[2 * H + j]; }
        else {
            b0 = a.enc_bih1[j]; b1 = a.enc_bih1[H + j]; b2 = a.enc_bih1[2 * H + j];
            b3 = a.enc_bhh1[j]; b4 = a.enc_bhh1[H + j]; b5 = a.enc_bhh1[2 * H + j];
        }
    }
    // gi prefetch (A lane0)
    float g0 = 0.f, g1 = 0.f, g2 = 0.f;
    if (isA && lane == 0) { g0 = a.gi_enc0[j]; g1 = a.gi_enc0[H + j]; g2 = a.gi_enc0[2 * H + j]; }

    const int tsw = isA ? 64 : 65;   // first phase using dec weights

    for (int p = 0; p <= 128; ++p) {
        // ---- stage current h via agent-scope loads ----
        {
            unsigned long long* h0u = (unsigned long long*)(a.h0buf + (p & 1) * H);
            unsigned long long* h1u = (unsigned long long*)(a.h1buf + (p & 1) * H);
            if (tid < 512) {
                unsigned long long v = __hip_atomic_load(h0u + tid, __ATOMIC_RELAXED, __HIP_MEMORY_SCOPE_AGENT);
                ((unsigned long long*)xh0)[tid] = v;
            } else {
                unsigned long long v = __hip_atomic_load(h1u + (tid - 512), __ATOMIC_RELAXED, __HIP_MEMORY_SCOPE_AGENT);
                ((unsigned long long*)xh1)[tid - 512] = v;
            }
        }
        __syncthreads();

        const bool hasA = (p <= 127), hasB = (p >= 1);
        if (isA) {
            if (hasA) {
                float s0 = 0.f, s1 = 0.f, s2 = 0.f;
                #pragma unroll
                for (int q = 0; q < 8; ++q) {
                    float x0 = xh0[lane + 128 * q];
                    float x1 = xh0[lane + 128 * q + 64];
                    s0 += lof(w0[q]) * x0 + hif(w0[q]) * x1;
                    s1 += lof(w1[q]) * x0 + hif(w1[q]) * x1;
                    s2 += lof(w2[q]) * x0 + hif(w2[q]) * x1;
                }
                #pragma unroll
                for (int m = 1; m < 64; m <<= 1) {
                    s0 += __shfl_xor(s0, m);
                    s1 += __shfl_xor(s1, m);
                    s2 += __shfl_xor(s2, m);
                }
                if (lane == 0) {
                    float r = sigmoidf_(g0 + s0 + b0);
                    float z = sigmoidf_(g1 + s1 + b1);
                    float n = tanhf(g2 + r * (s2 + b2));
                    float hn = (1.f - z) * n + z * xh0[j];
                    __hip_atomic_store(&a.h0buf[((p + 1) & 1) * H + j], hn,
                                       __ATOMIC_RELAXED, __HIP_MEMORY_SCOPE_AGENT);
                    if (p >= 64) a.states[(size_t)(p - 64) * 2048 + j] = hn;
                }
            }
        } else if (hasB) {
            float s0 = 0.f, s1 = 0.f, s2 = 0.f, s3 = 0.f, s4 = 0.f, s5 = 0.f;
            #pragma unroll
            for (int q = 0; q < 8; ++q) {
                float x0 = xh0[lane + 128 * q];
                float x1 = xh0[lane + 128 * q + 64];
                s0 += lof(w0[q]) * x0 + hif(w0[q]) * x1;
                s1 += lof(w1[q]) * x0 + hif(w1[q]) * x1;
                s2 += lof(w2[q]) * x0 + hif(w2[q]) * x1;
                float y0 = xh1[lane + 128 * q];
                float y1 = xh1[lane + 128 * q + 64];
                s3 += lof(w3[q]) * y0 + hif(w3[q]) * y1;
                s4 += lof(w4[q]) * y0 + hif(w4[q]) * y1;
                s5 += lof(w5[q]) * y0 + hif(w5[q]) * y1;
            }
            #pragma unroll
            for (int m = 1; m < 64; m <<= 1) {
                s0 += __shfl_xor(s0, m);
                s1 += __shfl_xor(s1, m);
                s2 += __shfl_xor(s2, m);
                s3 += __shfl_xor(s3, m);
                s4 += __shfl_xor(s4, m);
                s5 += __shfl_xor(s5, m);
            }
            if (lane == 0) {
                float r = sigmoidf_(s0 + b0 + s3 + b3);
                float z = sigmoidf_(s1 + b1 + s4 + b4);
                float n = tanhf(s2 + b2 + r * (s5 + b5));
                float hn = (1.f - z) * n + z * xh1[j];
                __hip_atomic_store(&a.h1buf[((p + 1) & 1) * H + j], hn,
                                   __ATOMIC_RELAXED, __HIP_MEMORY_SCOPE_AGENT);
                if (p >= 65) a.states[(size_t)(p - 65) * 2048 + H + j] = hn;
            }
        }

        // ---- prefetches overlapping the barrier ----
        if (isA && lane == 0 && p < 127) {
            const float* gn = (p + 1 < 64) ? (a.gi_enc0 + (size_t)(p + 1) * H3)
                                           : (a.gi_dec0 + (size_t)(p + 1 - 64) * H3);
            g0 = gn[j]; g1 = gn[H + j]; g2 = gn[2 * H + j];
        }
        if (p == tsw - 1) {
            if (isA) {
                loadw3(a.decWhh0, j, lane, w0, w1, w2);
                if (lane == 0) { b0 = a.dec_bhh0[j]; b1 = a.dec_bhh0[H + j]; b2 = a.dec_bhh0[2 * H + j]; }
            } else {
                loadw3(a.decWih1, j, lane, w0, w1, w2);
                loadw3(a.decWhh1, j, lane, w3, w4, w5);
                if (lane == 0) {
                    b0 = a.dec_bih1[j]; b1 = a.dec_bih1[H + j]; b2 = a.dec_bih1[2 * H + j];
                    b3 = a.dec_bhh1[j]; b4 = a.dec_bhh1[H + j]; b5 = a.dec_bhh1[2 * H + j];
                }
            }
        }

        if (p < 128) {
            // ---- grid barrier: 16 groups x 8 -> root -> 16 replicated flags ----
            __syncthreads();   // drains vmcnt -> h stores at coherent point
            if (tid == 0) {
                int g = bid >> 3;
                int* gc = a.bar + 64 + g * 16;
                int* gf = a.bar + 512 + g * 16;
                if ((__hip_atomic_fetch_add(gc, 1, __ATOMIC_RELAXED, __HIP_MEMORY_SCOPE_AGENT) & 7) == 7) {
                    if (__hip_atomic_fetch_add(a.bar + 32, 1, __ATOMIC_RELAXED, __HIP_MEMORY_SCOPE_AGENT) % 16 == 15) {
                        #pragma unroll
                        for (int gg = 0; gg < 16; ++gg)
                            __hip_atomic_store(a.bar + 512 + gg * 16, p + 1,
                                               __ATOMIC_RELAXED, __HIP_MEMORY_SCOPE_AGENT);
                    }
                }
                while (__hip_atomic_load(gf, __ATOMIC_RELAXED, __HIP_MEMORY_SCOPE_AGENT) < p + 1)
                    __builtin_amdgcn_s_sleep(1);
            }
            __syncthreads();
        }
    }
}

// ---------------- fallback per-phase kernel (f32; only if cooperative launch fails) ----------------
__global__ __launch_bounds__(384) void phase_kernel(
    const float* __restrict__ giA, const float* __restrict__ WhhA, const float* __restrict__ bhhA,
    const float* __restrict__ h0r, float* __restrict__ h0w, float* __restrict__ statesA, int hasA,
    const float* __restrict__ WihB, const float* __restrict__ bihB,
    const float* __restrict__ WhhB, const float* __restrict__ bhhB,
    const float* __restrict__ h1r, float* __restrict__ h1w, float* __restrict__ statesB, int hasB) {
    __shared__ float sred[8];
    int bid = blockIdx.x;
    int tid = threadIdx.x;
    int w = tid >> 6, lane = tid & 63;
    auto dotf = [&](const float* Wp, size_t roff, const float* x) -> float {
        float s = 0.f;
        const float* wrow = Wp + roff;
        #pragma unroll
        for (int i = 0; i < 4; ++i) {
            int k = lane * 4 + i * 256;
            float4 wv = *(const float4*)(wrow + k);
            float4 xv = *(const float4*)(x + k);
            s += wv.x * xv.x + wv.y * xv.y + wv.z * xv.z + wv.w * xv.w;
        }
        return s;
    };
    if (bid < 512) {
        if (!hasA) return;
        int tt = w / 3, g = w - tt * 3;
        int jj = bid * 2 + tt;
        float s = dotf(WhhA, (size_t)(g * H + jj) * H, h0r);
        #pragma unroll
        for (int m = 1; m < 64; m <<= 1) s += __shfl_xor(s, m);
        if (lane == 0) sred[w] = s;
        __syncthreads();
        if (tid < 2) {
            int j2 = bid * 2 + tid;
            float s0 = sred[tid * 3], s1 = sred[tid * 3 + 1], s2 = sred[tid * 3 + 2];
            float r = sigmoidf_(giA[j2] + s0 + bhhA[j2]);
            float z = sigmoidf_(giA[H + j2] + s1 + bhhA[H + j2]);
            float n = tanhf(giA[2 * H + j2] + r * (s2 + bhhA[2 * H + j2]));
            float hn = (1.f - z) * n + z * h0r[j2];
            h0w[j2] = hn;
            if (statesA) statesA[j2] = hn;
        }
    } else {
        if (!hasB) return;
        int j = bid - 512;
        int hh = (w >= 3);
        int g = w - hh * 3;
        float s = dotf(hh ? WhhB : WihB, (size_t)(g * H + j) * H, hh ? h1r : h0r);
        #pragma unroll
        for (int m = 1; m < 64; m <<= 1) s += __shfl_xor(s, m);
        if (lane == 0) sred[w] = s;
        __syncthreads();
        if (tid == 0) {
            float r = sigmoidf_(sred[0] + bihB[j] + sred[3] + bhhB[j]);
            float z = sigmoidf_(sred[1] + bihB[H + j] + sred[4] + bhhB[H + j]);
            float n = tanhf(sred[2] + bihB[2 * H + j] + r * (sred[5] + bhhB[2 * H + j]));
            float hn = (1.f - z) * n + z * h1r[j];
            h1w[j] = hn;
            if (statesB) statesB[j] = hn;
        }
    }
}

// ---------------- scores GEMM, split-K (f32 weights) ----------------
#define SN 64
#define SK 64
__global__ __launch_bounds__(256) void scores_kernel(const float* __restrict__ states,
                                                     const float* __restrict__ W,
                                                     const float* __restrict__ bias,
                                                     float* __restrict__ dst, int kc_count) {
    __shared__ float As[SK][64 + 1];
    __shared__ float Bs[SK][SN + 1];
    int n0 = blockIdx.x * SN;
    int kc = blockIdx.y;
    int klen = H / kc_count;
    int kbeg = kc * klen;
    int tid = threadIdx.x;
    int tn = tid & 15, tm = tid >> 4;
    float acc[4][4] = {};
    for (int k0 = kbeg; k0 < kbeg + klen; k0 += SK) {
        for (int i = tid; i < 64 * (SK / 4); i += 256) {
            int m = i >> 4;
            int kq = i & 15;
            float4 v = *(const float4*)(states + (size_t)m * 2048 + H + k0 + kq * 4);
            As[kq * 4 + 0][m] = v.x; As[kq * 4 + 1][m] = v.y;
            As[kq * 4 + 2][m] = v.z; As[kq * 4 + 3][m] = v.w;
        }
        for (int i = tid; i < SN * (SK / 4); i += 256) {
            int n = i >> 4;
            int kq = i & 15;
            int r = n0 + n;
            float4 v = make_float4(0.f, 0.f, 0.f, 0.f);
            if (r < V) v = *(const float4*)(W + (size_t)r * H + k0 + kq * 4);
            Bs[kq * 4 + 0][n] = v.x; Bs[kq * 4 + 1][n] = v.y;
            Bs[kq * 4 + 2][n] = v.z; Bs[kq * 4 + 3][n] = v.w;
        }
        __syncthreads();
        #pragma unroll 8
        for (int k = 0; k < SK; ++k) {
            float a[4], b[4];
            #pragma unroll
            for (int i = 0; i < 4; ++i) a[i] = As[k][tm * 4 + i];
            #pragma unroll
            for (int j = 0; j < 4; ++j) b[j] = Bs[k][tn * 4 + j];
            #pragma unroll
            for (int i = 0; i < 4; ++i)
                #pragma unroll
                for (int j = 0; j < 4; ++j) acc[i][j] += a[i] * b[j];
        }
        __syncthreads();
    }
    if (kc_count == 1) {
        #pragma unroll
        for (int i = 0; i < 4; ++i) {
            int m = tm * 4 + i;
            #pragma unroll
            for (int j = 0; j < 4; ++j) {
                int r = n0 + tn * 4 + j;
                if (r < V) dst[(size_t)m * V + r] = acc[i][j] + bias[r];
            }
        }
    } else {
        #pragma unroll
        for (int i = 0; i < 4; ++i) {
            int m = tm * 4 + i;
            #pragma unroll
            for (int j = 0; j < 4; ++j) {
                int r = n0 + tn * 4 + j;
                dst[(size_t)(kc * 64 + m) * NPAD + r] = acc[i][j];
            }
        }
    }
}

__global__ __launch_bounds__(256) void reduce_scores_kernel(const float* __restrict__ part,
                                                            const float* __restrict__ bias,
                                                            float* __restrict__ out, int kc_count) {
    int e = blockIdx.x * 256 + threadIdx.x;
    if (e >= 64 * V) return;
    int m = e / V, r = e - m * V;
    float s = bias[r];
    for (int kc = 0; kc < kc_count; ++kc)
        s += part[(size_t)(kc * 64 + m) * NPAD + r];
    out[(size_t)m * V + r] = s;
}

extern "C" void kernel_launch(void* const* d_in, const int* in_sizes, int n_in,
                              void* d_out, int out_size, void* d_ws, size_t ws_size,
                              hipStream_t stream) {
    const int*   char_seq  = (const int*)d_in[0];
    const float* enc_state = (const float*)d_in[1];
    const int*   sos       = (const int*)d_in[2];
    const int*   tgt       = (const int*)d_in[5];
    const float* emb       = (const float*)d_in[6];
    const float* enc_Wih0  = (const float*)d_in[7];
    const float* enc_Whh0  = (const float*)d_in[8];
    const float* enc_bih0  = (const float*)d_in[9];
    const float* enc_bhh0  = (const float*)d_in[10];
    const float* enc_Wih1  = (const float*)d_in[11];
    const float* enc_Whh1  = (const float*)d_in[12];
    const float* enc_bih1  = (const float*)d_in[13];
    const float* enc_bhh1  = (const float*)d_in[14];
    const float* dec_Wih0  = (const float*)d_in[15];
    const float* dec_Whh0  = (const float*)d_in[16];
    const float* dec_bih0  = (const float*)d_in[17];
    const float* dec_bhh0  = (const float*)d_in[18];
    const float* dec_Wih1  = (const float*)d_in[19];
    const float* dec_Whh1  = (const float*)d_in[20];
    const float* dec_bih1  = (const float*)d_in[21];
    const float* dec_bhh1  = (const float*)d_in[22];
    const float* out_W     = (const float*)d_in[23];
    const float* out_b     = (const float*)d_in[24];

    float* ws = (float*)d_ws;
    float* e_enc   = ws;                       // 64*512
    float* e_dec   = e_enc + SEQ * EMB;        // 64*512
    float* gi_enc0 = e_dec + SEQ * EMB;        // 64*3072
    float* gi_dec0 = gi_enc0 + SEQ * H3;       // 64*3072
    float* h0buf   = gi_dec0 + SEQ * H3;       // 2*1024
    float* h1buf   = h0buf + 2 * H;            // 2*1024
    int*   bar     = (int*)(h1buf + 2 * H);    // 1024 ints
    float* partials = h1buf + 2 * H + 1024;

    size_t base = (size_t)(partials - ws);
    size_t avail = ws_size / 4 > base ? ws_size / 4 - base : 0;
    int KC = 1;
    if (avail >= (size_t)8 * 64 * NPAD) KC = 8;
    else if (avail >= (size_t)4 * 64 * NPAD) KC = 4;
    else if (avail >= (size_t)2 * 64 * NPAD) KC = 2;

    float* scores = (float*)d_out;             // 64*10000
    float* states = scores + SEQ * V;          // 64*2048

    init_h_kernel<<<8, 256, 0, stream>>>(enc_state, h0buf, h1buf, bar);
    embed_kernel<<<128, 128, 0, stream>>>(char_seq, sos, tgt, emb, e_enc, e_dec);
    gi_gemm_kernel<<<dim3(H3 / 64, 2), 256, 0, stream>>>(e_enc, enc_Wih0, enc_bih0, gi_enc0,
                                                         e_dec, dec_Wih0, dec_bih0, gi_dec0);

    PArgs pa;
    pa.encWhh0 = enc_Whh0; pa.encWih1 = enc_Wih1; pa.encWhh1 = enc_Whh1;
    pa.decWhh0 = dec_Whh0; pa.decWih1 = dec_Wih1; pa.decWhh1 = dec_Whh1;
    pa.gi_enc0 = gi_enc0; pa.gi_dec0 = gi_dec0;
    pa.enc_bhh0 = enc_bhh0; pa.dec_bhh0 = dec_bhh0;
    pa.enc_bih1 = enc_bih1; pa.enc_bhh1 = enc_bhh1;
    pa.dec_bih1 = dec_bih1; pa.dec_bhh1 = dec_bhh1;
    pa.h0buf = h0buf; pa.h1buf = h1buf; pa.states = states;
    pa.bar = bar;
    void* kparams[] = { (void*)&pa };
    hipError_t err = hipLaunchCooperativeKernel((const void*)persist_kernel,
                                                dim3(128), dim3(1024), kparams, 0, stream);

    if (err != hipSuccess) {
        for (int p = 0; p <= 128; ++p) {
            int hasA = (p <= 127);
            int hasB = (p >= 1);
            const float* giA = nullptr; const float* WhhA = nullptr; const float* bhhA = nullptr;
            float* statesA = nullptr;
            if (hasA) {
                if (p < 64) { giA = gi_enc0 + (size_t)p * H3; WhhA = enc_Whh0; bhhA = enc_bhh0; }
                else {
                    int t = p - 64;
                    giA = gi_dec0 + (size_t)t * H3; WhhA = dec_Whh0; bhhA = dec_bhh0;
                    statesA = states + (size_t)t * 2048;
                }
            }
            const float *WihB = nullptr, *WhhB = nullptr, *bihB = nullptr, *bhhB = nullptr;
            float* statesB = nullptr;
            if (hasB) {
                if (p <= 64) { WihB = enc_Wih1; bihB = enc_bih1; WhhB = enc_Whh1; bhhB = enc_bhh1; }
                else {
                    int t = p - 65;
                    WihB = dec_Wih1; bihB = dec_bih1; WhhB = dec_Whh1; bhhB = dec_bhh1;
                    statesB = states + (size_t)t * 2048 + H;
                }
            }
            float* h0r = h0buf + (p & 1) * H;
            float* h0w = h0buf + ((p + 1) & 1) * H;
            float* h1r = h1buf + (p & 1) * H;
            float* h1w = h1buf + ((p + 1) & 1) * H;
            phase_kernel<<<1536, 384, 0, stream>>>(giA, WhhA, bhhA, h0r, h0w, statesA, hasA,
                                                   WihB, bihB, WhhB, bhhB, h1r, h1w, statesB, hasB);
        }
    }

    if (KC == 1) {
        scores_kernel<<<dim3((V + SN - 1) / SN, 1), 256, 0, stream>>>(states, out_W, out_b, scores, 1);
    } else {
        scores_kernel<<<dim3((V + SN - 1) / SN, KC), 256, 0, stream>>>(states, out_W, out_b, partials, KC);
        reduce_scores_kernel<<<(64 * V + 255) / 256, 256, 0, stream>>>(partials, out_b, scores, KC);
    }
}

// Round 9
// 739.973 us; speedup vs baseline: 1.3082x; 1.3082x over previous
//
#include <hip/hip_runtime.h>
#include <hip/hip_bf16.h>
#include <math.h>

#define V     10000
#define EMB   512
#define H     1024
#define H3    3072
#define SEQ   64
#define NPAD  10048   // 157*64, padded N for score partials

typedef __attribute__((ext_vector_type(8))) unsigned short us8;
typedef __attribute__((ext_vector_type(8))) unsigned u32x8;

__device__ __forceinline__ float sigmoidf_(float x) { return 1.0f / (1.0f + expf(-x)); }
__device__ __forceinline__ float bf2f(unsigned short u) { return __uint_as_float(((unsigned)u) << 16); }
__device__ __forceinline__ float lof(unsigned u) { return __uint_as_float(u << 16); }
__device__ __forceinline__ float hif(unsigned u) { return __uint_as_float(u & 0xffff0000u); }
__device__ __forceinline__ unsigned short f2bf_rne(float f) {
    unsigned u = __float_as_uint(f);
    unsigned r = u + 0x7FFF + ((u >> 16) & 1);
    return (unsigned short)(r >> 16);
}

// ---------------- f32 -> bf16 conversion of the 6 recurrent matrices (one launch) ----------------
struct CvtArgs { const float* src[6]; unsigned short* dst0; };
__global__ __launch_bounds__(256) void f2bf6_kernel(CvtArgs c) {
    const float* src = c.src[blockIdx.y];
    unsigned short* dst = c.dst0 + (size_t)blockIdx.y * ((size_t)H3 * H);
    int i = (blockIdx.x * 256 + threadIdx.x) * 8;
    float4 a = *(const float4*)(src + i);
    float4 b = *(const float4*)(src + i + 4);
    us8 o;
    o[0] = f2bf_rne(a.x); o[1] = f2bf_rne(a.y); o[2] = f2bf_rne(a.z); o[3] = f2bf_rne(a.w);
    o[4] = f2bf_rne(b.x); o[5] = f2bf_rne(b.y); o[6] = f2bf_rne(b.z); o[7] = f2bf_rne(b.w);
    *(us8*)(dst + i) = o;
}

// ---------------- init: h ping-pong buffers + barrier counters ----------------
__global__ void init_h_kernel(const float* __restrict__ enc_state,
                              float* __restrict__ h0buf, float* __restrict__ h1buf,
                              int* __restrict__ bar) {
    int i = blockIdx.x * blockDim.x + threadIdx.x;
    if (i < H)            h0buf[i] = enc_state[i];
    else if (i < 2 * H)   h1buf[H + (i - H)] = enc_state[i];
    if (i < 1024) bar[i] = 0;
}

// ---------------- embedding gather ----------------
__global__ void embed_kernel(const int* __restrict__ cs, const int* __restrict__ sos,
                             const int* __restrict__ tgt, const float* __restrict__ emb,
                             float* __restrict__ e_enc, float* __restrict__ e_dec) {
    int t = blockIdx.x;  // 0..127
    int id;
    float* dst;
    if (t < SEQ) { id = cs[t]; dst = e_enc + (size_t)t * EMB; }
    else         { int td = t - SEQ; id = (td == 0) ? sos[0] : tgt[td - 1]; dst = e_dec + (size_t)td * EMB; }
    const float4* src4 = (const float4*)(emb + (size_t)id * EMB);
    float4* dst4 = (float4*)dst;
    dst4[threadIdx.x] = src4[threadIdx.x];
}

// ---------------- gi0 as tiled GEMM, batched over {enc,dec}: out = e @ W.T + b ----------------
__global__ __launch_bounds__(256) void gi_gemm_kernel(const float* __restrict__ Ae, const float* __restrict__ We,
                                                      const float* __restrict__ be, float* __restrict__ oe,
                                                      const float* __restrict__ Ad, const float* __restrict__ Wd,
                                                      const float* __restrict__ bd, float* __restrict__ od) {
    __shared__ float As[64][64 + 1];
    __shared__ float Bs[64][64 + 1];
    const float* A = blockIdx.y ? Ad : Ae;
    const float* W = blockIdx.y ? Wd : We;
    const float* bias = blockIdx.y ? bd : be;
    float* out = blockIdx.y ? od : oe;
    int n0 = blockIdx.x * 64;
    int tid = threadIdx.x;
    int tn = tid & 15, tm = tid >> 4;
    float acc[4][4] = {};
    for (int k0 = 0; k0 < EMB; k0 += 64) {
        for (int i = tid; i < 64 * 16; i += 256) {
            int m = i >> 4, kq = i & 15;
            float4 v = *(const float4*)(A + (size_t)m * EMB + k0 + kq * 4);
            As[kq * 4 + 0][m] = v.x; As[kq * 4 + 1][m] = v.y;
            As[kq * 4 + 2][m] = v.z; As[kq * 4 + 3][m] = v.w;
        }
        for (int i = tid; i < 64 * 16; i += 256) {
            int n = i >> 4, kq = i & 15;
            float4 v = *(const float4*)(W + (size_t)(n0 + n) * EMB + k0 + kq * 4);
            Bs[kq * 4 + 0][n] = v.x; Bs[kq * 4 + 1][n] = v.y;
            Bs[kq * 4 + 2][n] = v.z; Bs[kq * 4 + 3][n] = v.w;
        }
        __syncthreads();
        #pragma unroll 8
        for (int k = 0; k < 64; ++k) {
            float a[4], b[4];
            #pragma unroll
            for (int i = 0; i < 4; ++i) a[i] = As[k][tm * 4 + i];
            #pragma unroll
            for (int j = 0; j < 4; ++j) b[j] = Bs[k][tn * 4 + j];
            #pragma unroll
            for (int i = 0; i < 4; ++i)
                #pragma unroll
                for (int j = 0; j < 4; ++j) acc[i][j] += a[i] * b[j];
        }
        __syncthreads();
    }
    #pragma unroll
    for (int i = 0; i < 4; ++i) {
        int m = tm * 4 + i;
        #pragma unroll
        for (int j = 0; j < 4; ++j) {
            int r = n0 + tn * 4 + j;
            out[(size_t)m * H3 + r] = acc[i][j] + bias[r];
        }
    }
}

// ================= persistent recurrence kernel (v6: R6 compute + 2-hop barrier) =================
// 192 blocks x 1024 threads (16 waves). Blocks 0..63 = A (layer0): wave w -> j = bid*16+w,
// 3 gate rows in 24 packed VGPRs (bf16 pre-converted). Blocks 64..191 = B (layer1):
// j = (bid-64)*8 + (w>>1); part = w&1 (0: Wih rows, 1: Whh rows); LDS sred finalize.
// h exchange via agent-scope relaxed atomics. Barrier: 24 group counters (8 blocks each,
// monotonic); arrive = 1 add; release = tid<24 poll ALL 24 counters (R7 showed polling
// contention is harmless; this deletes the root + flag hops from the serial chain).
struct PArgs {
    const unsigned short *encWhh0, *encWih1, *encWhh1;
    const unsigned short *decWhh0, *decWih1, *decWhh1;
    const float *gi_enc0, *gi_dec0;
    const float *enc_bhh0, *dec_bhh0;
    const float *enc_bih1, *enc_bhh1, *dec_bih1, *dec_bhh1;
    float *h0buf, *h1buf, *states;
    int *bar;   // [64 + g*16] = 24 group arrival counters (1 cacheline each)
};

__device__ __forceinline__ void loadw24(const unsigned short* __restrict__ m,
                                        int j, int lane,
                                        u32x8& w0, u32x8& w1, u32x8& w2) {
    size_t b0 = (size_t)j * H + lane;
    size_t b1 = (size_t)(H + j) * H + lane;
    size_t b2 = (size_t)(2 * H + j) * H + lane;
    #pragma unroll
    for (int q = 0; q < 8; ++q) {
        w0[q] = (unsigned)m[b0 + 128 * q] | ((unsigned)m[b0 + 128 * q + 64] << 16);
        w1[q] = (unsigned)m[b1 + 128 * q] | ((unsigned)m[b1 + 128 * q + 64] << 16);
        w2[q] = (unsigned)m[b2 + 128 * q] | ((unsigned)m[b2 + 128 * q + 64] << 16);
    }
}

__global__ __launch_bounds__(1024, 4) void persist_kernel(PArgs a) {
    __shared__ __align__(16) float xh0[H];
    __shared__ __align__(16) float xh1[H];
    __shared__ float sred[64];
    const int tid = threadIdx.x;
    const int w = tid >> 6, lane = tid & 63;
    const int bid = blockIdx.x;
    const bool isA = (bid < 64);
    int j, part = 0;
    if (isA) j = bid * 16 + w;
    else { int bb = bid - 64; j = bb * 8 + (w >> 1); part = w & 1; }

    const unsigned short* menc = isA ? a.encWhh0 : (part == 0 ? a.encWih1 : a.encWhh1);
    const unsigned short* mdec = isA ? a.decWhh0 : (part == 0 ? a.decWih1 : a.decWhh1);
    const int tsw = isA ? 64 : 65;   // first phase that uses dec weights

    u32x8 w0, w1, w2;
    loadw24(menc, j, lane, w0, w1, w2);

    // hoisted biases: A (lane0) b0..b2 = bhh rows; B (tid<8) b0..b5 = bih,bhh
    float b0 = 0.f, b1 = 0.f, b2 = 0.f, b3 = 0.f, b4 = 0.f, b5 = 0.f;
    if (isA) {
        if (lane == 0) { b0 = a.enc_bhh0[j]; b1 = a.enc_bhh0[H + j]; b2 = a.enc_bhh0[2 * H + j]; }
    } else if (tid < 8) {
        int jg = (bid - 64) * 8 + tid;
        b0 = a.enc_bih1[jg]; b1 = a.enc_bih1[H + jg]; b2 = a.enc_bih1[2 * H + jg];
        b3 = a.enc_bhh1[jg]; b4 = a.enc_bhh1[H + jg]; b5 = a.enc_bhh1[2 * H + jg];
    }
    // gi prefetch (A lane0)
    float g0 = 0.f, g1 = 0.f, g2 = 0.f;
    if (isA && lane == 0) { g0 = a.gi_enc0[j]; g1 = a.gi_enc0[H + j]; g2 = a.gi_enc0[2 * H + j]; }

    for (int p = 0; p <= 128; ++p) {
        // ---- stage current h via agent-scope loads ----
        {
            unsigned long long* h0u = (unsigned long long*)(a.h0buf + (p & 1) * H);
            unsigned long long* h1u = (unsigned long long*)(a.h1buf + (p & 1) * H);
            if (tid < 512) {
                unsigned long long v = __hip_atomic_load(h0u + tid, __ATOMIC_RELAXED, __HIP_MEMORY_SCOPE_AGENT);
                ((unsigned long long*)xh0)[tid] = v;
            } else {
                unsigned long long v = __hip_atomic_load(h1u + (tid - 512), __ATOMIC_RELAXED, __HIP_MEMORY_SCOPE_AGENT);
                ((unsigned long long*)xh1)[tid - 512] = v;
            }
        }
        __syncthreads();

        const bool hasA = (p <= 127), hasB = (p >= 1);
        if (isA ? hasA : hasB) {
            const float* x = (isA || part == 0) ? xh0 : xh1;
            float s0 = 0.f, s1 = 0.f, s2 = 0.f;
            #pragma unroll
            for (int q = 0; q < 8; ++q) {
                float x0 = x[lane + 128 * q];
                float x1 = x[lane + 128 * q + 64];
                s0 += lof(w0[q]) * x0 + hif(w0[q]) * x1;
                s1 += lof(w1[q]) * x0 + hif(w1[q]) * x1;
                s2 += lof(w2[q]) * x0 + hif(w2[q]) * x1;
            }
            #pragma unroll
            for (int m = 1; m < 64; m <<= 1) {
                s0 += __shfl_xor(s0, m);
                s1 += __shfl_xor(s1, m);
                s2 += __shfl_xor(s2, m);
            }
            if (isA) {
                if (lane == 0) {
                    float r = sigmoidf_(g0 + s0 + b0);
                    float z = sigmoidf_(g1 + s1 + b1);
                    float n = tanhf(g2 + r * (s2 + b2));
                    float hn = (1.f - z) * n + z * xh0[j];
                    __hip_atomic_store(&a.h0buf[((p + 1) & 1) * H + j], hn,
                                       __ATOMIC_RELAXED, __HIP_MEMORY_SCOPE_AGENT);
                    if (p >= 64) a.states[(size_t)(p - 64) * 2048 + j] = hn;
                }
            } else if (lane == 0) {
                int slot = (w >> 1) * 8 + part * 4;
                sred[slot + 0] = s0; sred[slot + 1] = s1; sred[slot + 2] = s2;
            }
        }
        __syncthreads();
        if (!isA && hasB && tid < 8) {
            int jg = (bid - 64) * 8 + tid;
            float si0 = sred[tid * 8 + 0], si1 = sred[tid * 8 + 1], si2 = sred[tid * 8 + 2];
            float sh0 = sred[tid * 8 + 4], sh1 = sred[tid * 8 + 5], sh2 = sred[tid * 8 + 6];
            float r = sigmoidf_(si0 + b0 + sh0 + b3);
            float z = sigmoidf_(si1 + b1 + sh1 + b4);
            float n = tanhf(si2 + b2 + r * (sh2 + b5));
            float hn = (1.f - z) * n + z * xh1[jg];
            __hip_atomic_store(&a.h1buf[((p + 1) & 1) * H + jg], hn,
                               __ATOMIC_RELAXED, __HIP_MEMORY_SCOPE_AGENT);
            if (p >= 65) a.states[(size_t)(p - 65) * 2048 + H + jg] = hn;
        }
        // ---- prefetches overlapping the barrier ----
        if (isA && lane == 0 && p < 127) {
            const float* gn = (p + 1 < 64) ? (a.gi_enc0 + (size_t)(p + 1) * H3)
                                           : (a.gi_dec0 + (size_t)(p + 1 - 64) * H3);
            g0 = gn[j]; g1 = gn[H + j]; g2 = gn[2 * H + j];
        }
        if (p == tsw - 1) {
            loadw24(mdec, j, lane, w0, w1, w2);
            if (isA) {
                if (lane == 0) { b0 = a.dec_bhh0[j]; b1 = a.dec_bhh0[H + j]; b2 = a.dec_bhh0[2 * H + j]; }
            } else if (tid < 8) {
                int jg = (bid - 64) * 8 + tid;
                b0 = a.dec_bih1[jg]; b1 = a.dec_bih1[H + jg]; b2 = a.dec_bih1[2 * H + jg];
                b3 = a.dec_bhh1[jg]; b4 = a.dec_bhh1[H + jg]; b5 = a.dec_bhh1[2 * H + jg];
            }
        }

        if (p < 128) {
            // ---- 2-hop grid barrier: arrive-add, then poll all 24 group counters ----
            __syncthreads();   // drains vmcnt -> h stores at coherent point
            if (tid < 24) {
                if (tid == 0)
                    __hip_atomic_fetch_add(a.bar + 64 + (bid >> 3) * 16, 1,
                                           __ATOMIC_RELAXED, __HIP_MEMORY_SCOPE_AGENT);
                const int target = 8 * (p + 1);
                while (__hip_atomic_load(a.bar + 64 + tid * 16,
                                         __ATOMIC_RELAXED, __HIP_MEMORY_SCOPE_AGENT) < target)
                    __builtin_amdgcn_s_sleep(1);
            }
            __syncthreads();
        }
    }
}

// ---------------- fallback per-phase kernel (only if cooperative launch fails) ----------------
template<int BF>
__global__ __launch_bounds__(384) void phase_kernel(
    const float* __restrict__ giA, const void* __restrict__ WhhA, const float* __restrict__ bhhA,
    const float* __restrict__ h0r, float* __restrict__ h0w, float* __restrict__ statesA, int hasA,
    const void* __restrict__ WihB, const float* __restrict__ bihB,
    const void* __restrict__ WhhB, const float* __restrict__ bhhB,
    const float* __restrict__ h1r, float* __restrict__ h1w, float* __restrict__ statesB, int hasB) {
    __shared__ float sred[8];
    int bid = blockIdx.x;
    int tid = threadIdx.x;
    int w = tid >> 6, lane = tid & 63;
    auto dotf = [&](const void* Wp, size_t roff, const float* x) -> float {
        float s = 0.f;
        if (BF) {
            const unsigned short* wrow = (const unsigned short*)Wp + roff;
            #pragma unroll
            for (int i = 0; i < 2; ++i) {
                int k = lane * 8 + i * 512;
                us8 wv = *(const us8*)(wrow + k);
                float4 x0 = *(const float4*)(x + k);
                float4 x1 = *(const float4*)(x + k + 4);
                s += bf2f(wv[0]) * x0.x + bf2f(wv[1]) * x0.y + bf2f(wv[2]) * x0.z + bf2f(wv[3]) * x0.w
                   + bf2f(wv[4]) * x1.x + bf2f(wv[5]) * x1.y + bf2f(wv[6]) * x1.z + bf2f(wv[7]) * x1.w;
            }
        } else {
            const float* wrow = (const float*)Wp + roff;
            #pragma unroll
            for (int i = 0; i < 4; ++i) {
                int k = lane * 4 + i * 256;
                float4 wv = *(const float4*)(wrow + k);
                float4 xv = *(const float4*)(x + k);
                s += wv.x * xv.x + wv.y * xv.y + wv.z * xv.z + wv.w * xv.w;
            }
        }
        return s;
    };
    if (bid < 512) {
        if (!hasA) return;
        int tt = w / 3, g = w - tt * 3;
        int jj = bid * 2 + tt;
        float s = dotf(WhhA, (size_t)(g * H + jj) * H, h0r);
        #pragma unroll
        for (int m = 1; m < 64; m <<= 1) s += __shfl_xor(s, m);
        if (lane == 0) sred[w] = s;
        __syncthreads();
        if (tid < 2) {
            int j2 = bid * 2 + tid;
            float s0 = sred[tid * 3], s1 = sred[tid * 3 + 1], s2 = sred[tid * 3 + 2];
            float r = sigmoidf_(giA[j2] + s0 + bhhA[j2]);
            float z = sigmoidf_(giA[H + j2] + s1 + bhhA[H + j2]);
            float n = tanhf(giA[2 * H + j2] + r * (s2 + bhhA[2 * H + j2]));
            float hn = (1.f - z) * n + z * h0r[j2];
            h0w[j2] = hn;
            if (statesA) statesA[j2] = hn;
        }
    } else {
        if (!hasB) return;
        int j = bid - 512;
        int hh = (w >= 3);
        int g = w - hh * 3;
        float s = dotf(hh ? WhhB : WihB, (size_t)(g * H + j) * H, hh ? h1r : h0r);
        #pragma unroll
        for (int m = 1; m < 64; m <<= 1) s += __shfl_xor(s, m);
        if (lane == 0) sred[w] = s;
        __syncthreads();
        if (tid == 0) {
            float r = sigmoidf_(sred[0] + bihB[j] + sred[3] + bhhB[j]);
            float z = sigmoidf_(sred[1] + bihB[H + j] + sred[4] + bhhB[H + j]);
            float n = tanhf(sred[2] + bihB[2 * H + j] + r * (sred[5] + bhhB[2 * H + j]));
            float hn = (1.f - z) * n + z * h1r[j];
            h1w[j] = hn;
            if (statesB) statesB[j] = hn;
        }
    }
}

// ---------------- scores GEMM, split-K (f32 weights) ----------------
#define SN 64
#define SK 64
__global__ __launch_bounds__(256) void scores_kernel(const float* __restrict__ states,
                                                     const float* __restrict__ W,
                                                     const float* __restrict__ bias,
                                                     float* __restrict__ dst, int kc_count) {
    __shared__ float As[SK][64 + 1];
    __shared__ float Bs[SK][SN + 1];
    int n0 = blockIdx.x * SN;
    int kc = blockIdx.y;
    int klen = H / kc_count;
    int kbeg = kc * klen;
    int tid = threadIdx.x;
    int tn = tid & 15, tm = tid >> 4;
    float acc[4][4] = {};
    for (int k0 = kbeg; k0 < kbeg + klen; k0 += SK) {
        for (int i = tid; i < 64 * (SK / 4); i += 256) {
            int m = i >> 4;
            int kq = i & 15;
            float4 v = *(const float4*)(states + (size_t)m * 2048 + H + k0 + kq * 4);
            As[kq * 4 + 0][m] = v.x; As[kq * 4 + 1][m] = v.y;
            As[kq * 4 + 2][m] = v.z; As[kq * 4 + 3][m] = v.w;
        }
        for (int i = tid; i < SN * (SK / 4); i += 256) {
            int n = i >> 4;
            int kq = i & 15;
            int r = n0 + n;
            float4 v = make_float4(0.f, 0.f, 0.f, 0.f);
            if (r < V) v = *(const float4*)(W + (size_t)r * H + k0 + kq * 4);
            Bs[kq * 4 + 0][n] = v.x; Bs[kq * 4 + 1][n] = v.y;
            Bs[kq * 4 + 2][n] = v.z; Bs[kq * 4 + 3][n] = v.w;
        }
        __syncthreads();
        #pragma unroll 8
        for (int k = 0; k < SK; ++k) {
            float a[4], b[4];
            #pragma unroll
            for (int i = 0; i < 4; ++i) a[i] = As[k][tm * 4 + i];
            #pragma unroll
            for (int j = 0; j < 4; ++j) b[j] = Bs[k][tn * 4 + j];
            #pragma unroll
            for (int i = 0; i < 4; ++i)
                #pragma unroll
                for (int j = 0; j < 4; ++j) acc[i][j] += a[i] * b[j];
        }
        __syncthreads();
    }
    if (kc_count == 1) {
        #pragma unroll
        for (int i = 0; i < 4; ++i) {
            int m = tm * 4 + i;
            #pragma unroll
            for (int j = 0; j < 4; ++j) {
                int r = n0 + tn * 4 + j;
                if (r < V) dst[(size_t)m * V + r] = acc[i][j] + bias[r];
            }
        }
    } else {
        #pragma unroll
        for (int i = 0; i < 4; ++i) {
            int m = tm * 4 + i;
            #pragma unroll
            for (int j = 0; j < 4; ++j) {
                int r = n0 + tn * 4 + j;
                dst[(size_t)(kc * 64 + m) * NPAD + r] = acc[i][j];
            }
        }
    }
}

__global__ __launch_bounds__(256) void reduce_scores_kernel(const float* __restrict__ part,
                                                            const float* __restrict__ bias,
                                                            float* __restrict__ out, int kc_count) {
    int e = blockIdx.x * 256 + threadIdx.x;
    if (e >= 64 * V) return;
    int m = e / V, r = e - m * V;
    float s = bias[r];
    for (int kc = 0; kc < kc_count; ++kc)
        s += part[(size_t)(kc * 64 + m) * NPAD + r];
    out[(size_t)m * V + r] = s;
}

extern "C" void kernel_launch(void* const* d_in, const int* in_sizes, int n_in,
                              void* d_out, int out_size, void* d_ws, size_t ws_size,
                              hipStream_t stream) {
    const int*   char_seq  = (const int*)d_in[0];
    const float* enc_state = (const float*)d_in[1];
    const int*   sos       = (const int*)d_in[2];
    const int*   tgt       = (const int*)d_in[5];
    const float* emb       = (const float*)d_in[6];
    const float* enc_Wih0  = (const float*)d_in[7];
    const float* enc_Whh0  = (const float*)d_in[8];
    const float* enc_bih0  = (const float*)d_in[9];
    const float* enc_bhh0  = (const float*)d_in[10];
    const float* enc_Wih1  = (const float*)d_in[11];
    const float* enc_Whh1  = (const float*)d_in[12];
    const float* enc_bih1  = (const float*)d_in[13];
    const float* enc_bhh1  = (const float*)d_in[14];
    const float* dec_Wih0  = (const float*)d_in[15];
    const float* dec_Whh0  = (const float*)d_in[16];
    const float* dec_bih0  = (const float*)d_in[17];
    const float* dec_bhh0  = (const float*)d_in[18];
    const float* dec_Wih1  = (const float*)d_in[19];
    const float* dec_Whh1  = (const float*)d_in[20];
    const float* dec_bih1  = (const float*)d_in[21];
    const float* dec_bhh1  = (const float*)d_in[22];
    const float* out_W     = (const float*)d_in[23];
    const float* out_b     = (const float*)d_in[24];

    float* ws = (float*)d_ws;
    float* e_enc   = ws;                       // 64*512
    float* e_dec   = e_enc + SEQ * EMB;        // 64*512
    float* gi_enc0 = e_dec + SEQ * EMB;        // 64*3072
    float* gi_dec0 = gi_enc0 + SEQ * H3;       // 64*3072
    float* h0buf   = gi_dec0 + SEQ * H3;       // 2*1024
    float* h1buf   = h0buf + 2 * H;            // 2*1024
    int*   bar     = (int*)(h1buf + 2 * H);    // 1024 ints
    float* cur     = h1buf + 2 * H + 1024;
    size_t base = (size_t)(cur - ws);
    size_t avail = ws_size / 4 > base ? ws_size / 4 - base : 0;

    const size_t REC_ELEMS = (size_t)H3 * H;   // per matrix
    const size_t REC_SLOTS = REC_ELEMS / 2;    // float-slots per bf16 matrix

    int bf_rec = (avail >= 6 * REC_SLOTS);
    unsigned short* wbf0 = nullptr;
    if (bf_rec) { wbf0 = (unsigned short*)cur; cur += 6 * REC_SLOTS; avail -= 6 * REC_SLOTS; }
    int KC = 1;
    if (avail >= (size_t)8 * 64 * NPAD) KC = 8;
    else if (avail >= (size_t)4 * 64 * NPAD) KC = 4;
    else if (avail >= (size_t)2 * 64 * NPAD) KC = 2;
    float* partials = cur;

    float* scores = (float*)d_out;             // 64*10000
    float* states = scores + SEQ * V;          // 64*2048

    if (bf_rec) {
        CvtArgs c;
        c.src[0] = enc_Whh0; c.src[1] = enc_Wih1; c.src[2] = enc_Whh1;
        c.src[3] = dec_Whh0; c.src[4] = dec_Wih1; c.src[5] = dec_Whh1;
        c.dst0 = wbf0;
        f2bf6_kernel<<<dim3((unsigned)(REC_ELEMS / 2048), 6), 256, 0, stream>>>(c);
    }
    init_h_kernel<<<8, 256, 0, stream>>>(enc_state, h0buf, h1buf, bar);
    embed_kernel<<<128, 128, 0, stream>>>(char_seq, sos, tgt, emb, e_enc, e_dec);
    gi_gemm_kernel<<<dim3(H3 / 64, 2), 256, 0, stream>>>(e_enc, enc_Wih0, enc_bih0, gi_enc0,
                                                         e_dec, dec_Wih0, dec_bih0, gi_dec0);

    bool done = false;
    if (bf_rec) {
        PArgs pa;
        pa.encWhh0 = wbf0;
        pa.encWih1 = wbf0 + REC_ELEMS;
        pa.encWhh1 = wbf0 + 2 * REC_ELEMS;
        pa.decWhh0 = wbf0 + 3 * REC_ELEMS;
        pa.decWih1 = wbf0 + 4 * REC_ELEMS;
        pa.decWhh1 = wbf0 + 5 * REC_ELEMS;
        pa.gi_enc0 = gi_enc0; pa.gi_dec0 = gi_dec0;
        pa.enc_bhh0 = enc_bhh0; pa.dec_bhh0 = dec_bhh0;
        pa.enc_bih1 = enc_bih1; pa.enc_bhh1 = enc_bhh1;
        pa.dec_bih1 = dec_bih1; pa.dec_bhh1 = dec_bhh1;
        pa.h0buf = h0buf; pa.h1buf = h1buf; pa.states = states;
        pa.bar = bar;
        void* kparams[] = { (void*)&pa };
        hipError_t err = hipLaunchCooperativeKernel((const void*)persist_kernel,
                                                    dim3(192), dim3(1024), kparams, 0, stream);
        done = (err == hipSuccess);
    }

    if (!done) {
        for (int p = 0; p <= 128; ++p) {
            int hasA = (p <= 127);
            int hasB = (p >= 1);
            const float* giA = nullptr; const void* WhhA = nullptr; const float* bhhA = nullptr;
            float* statesA = nullptr;
            if (hasA) {
                if (p < 64) {
                    giA = gi_enc0 + (size_t)p * H3; bhhA = enc_bhh0;
                    WhhA = bf_rec ? (const void*)wbf0 : (const void*)enc_Whh0;
                } else {
                    int t = p - 64;
                    giA = gi_dec0 + (size_t)t * H3; bhhA = dec_bhh0;
                    WhhA = bf_rec ? (const void*)(wbf0 + 3 * REC_ELEMS) : (const void*)dec_Whh0;
                    statesA = states + (size_t)t * 2048;
                }
            }
            const void *WihB = nullptr, *WhhB = nullptr;
            const float *bihB = nullptr, *bhhB = nullptr;
            float* statesB = nullptr;
            if (hasB) {
                if (p <= 64) {
                    bihB = enc_bih1; bhhB = enc_bhh1;
                    WihB = bf_rec ? (const void*)(wbf0 + REC_ELEMS) : (const void*)enc_Wih1;
                    WhhB = bf_rec ? (const void*)(wbf0 + 2 * REC_ELEMS) : (const void*)enc_Whh1;
                } else {
                    int t = p - 65;
                    bihB = dec_bih1; bhhB = dec_bhh1;
                    WihB = bf_rec ? (const void*)(wbf0 + 4 * REC_ELEMS) : (const void*)dec_Wih1;
                    WhhB = bf_rec ? (const void*)(wbf0 + 5 * REC_ELEMS) : (const void*)dec_Whh1;
                    statesB = states + (size_t)t * 2048 + H;
                }
            }
            float* h0r = h0buf + (p & 1) * H;
            float* h0w = h0buf + ((p + 1) & 1) * H;
            float* h1r = h1buf + (p & 1) * H;
            float* h1w = h1buf + ((p + 1) & 1) * H;
            if (bf_rec)
                phase_kernel<1><<<1536, 384, 0, stream>>>(giA, WhhA, bhhA, h0r, h0w, statesA, hasA,
                                                          WihB, bihB, WhhB, bhhB, h1r, h1w, statesB, hasB);
            else
                phase_kernel<0><<<1536, 384, 0, stream>>>(giA, WhhA, bhhA, h0r, h0w, statesA, hasA,
                                                          WihB, bihB, WhhB, bhhB, h1r, h1w, statesB, hasB);
        }
    }

    if (KC == 1) {
        scores_kernel<<<dim3((V + SN - 1) / SN, 1), 256, 0, stream>>>(states, out_W, out_b, scores, 1);
    } else {
        scores_kernel<<<dim3((V + SN - 1) / SN, KC), 256, 0, stream>>>(states, out_W, out_b, partials, KC);
        reduce_scores_kernel<<<(64 * V + 255) / 256, 256, 0, stream>>>(partials, out_b, scores, KC);
    }
}

// Round 10
// 535.914 us; speedup vs baseline: 1.8063x; 1.3808x over previous
//
#include <hip/hip_runtime.h>
#include <hip/hip_bf16.h>
#include <math.h>

#define V     10000
#define EMB   512
#define H     1024
#define H3    3072
#define SEQ   64
#define NPAD  10048   // 157*64, padded N for score partials
#define NPH   129     // history slots (phases 0..128)

typedef __attribute__((ext_vector_type(8))) unsigned short us8;
typedef __attribute__((ext_vector_type(8))) unsigned u32x8;
typedef unsigned long long ull;

__device__ __forceinline__ float sigmoidf_(float x) { return 1.0f / (1.0f + expf(-x)); }
__device__ __forceinline__ float bf2f(unsigned short u) { return __uint_as_float(((unsigned)u) << 16); }
__device__ __forceinline__ float lof(unsigned u) { return __uint_as_float(u << 16); }
__device__ __forceinline__ float hif(unsigned u) { return __uint_as_float(u & 0xffff0000u); }
__device__ __forceinline__ unsigned short f2bf_rne(float f) {
    unsigned u = __float_as_uint(f);
    unsigned r = u + 0x7FFF + ((u >> 16) & 1);
    return (unsigned short)(r >> 16);
}
__device__ __forceinline__ ull packh(float v) {
    return (ull)__float_as_uint(v) | (1ULL << 32);
}

// ---------------- f32 -> bf16 conversion of the 6 recurrent matrices (one launch) ----------------
struct CvtArgs { const float* src[6]; unsigned short* dst0; };
__global__ __launch_bounds__(256) void f2bf6_kernel(CvtArgs c) {
    const float* src = c.src[blockIdx.y];
    unsigned short* dst = c.dst0 + (size_t)blockIdx.y * ((size_t)H3 * H);
    int i = (blockIdx.x * 256 + threadIdx.x) * 8;
    float4 a = *(const float4*)(src + i);
    float4 b = *(const float4*)(src + i + 4);
    us8 o;
    o[0] = f2bf_rne(a.x); o[1] = f2bf_rne(a.y); o[2] = f2bf_rne(a.z); o[3] = f2bf_rne(a.w);
    o[4] = f2bf_rne(b.x); o[5] = f2bf_rne(b.y); o[6] = f2bf_rne(b.z); o[7] = f2bf_rne(b.w);
    *(us8*)(dst + i) = o;
}

// ---------------- init: zero tagged history, write phase-0 slots, fallback h buffers ----------------
__global__ __launch_bounds__(256) void init2_kernel(const float* __restrict__ enc_state,
                                                    ull* __restrict__ h0hist, ull* __restrict__ h1hist,
                                                    float* __restrict__ h0buf, float* __restrict__ h1buf) {
    int i = blockIdx.x * 256 + threadIdx.x;
    if (i >= NPH * 1024) return;
    ull v0 = 0, v1 = 0;
    if (i < 1024) {
        v0 = packh(enc_state[i]);
        v1 = packh(enc_state[H + i]);
        h0buf[i] = enc_state[i];          // fallback path init
        h1buf[H + i] = enc_state[H + i];
    }
    h0hist[i] = v0;
    h1hist[i] = v1;
}

// ---------------- embedding gather ----------------
__global__ void embed_kernel(const int* __restrict__ cs, const int* __restrict__ sos,
                             const int* __restrict__ tgt, const float* __restrict__ emb,
                             float* __restrict__ e_enc, float* __restrict__ e_dec) {
    int t = blockIdx.x;  // 0..127
    int id;
    float* dst;
    if (t < SEQ) { id = cs[t]; dst = e_enc + (size_t)t * EMB; }
    else         { int td = t - SEQ; id = (td == 0) ? sos[0] : tgt[td - 1]; dst = e_dec + (size_t)td * EMB; }
    const float4* src4 = (const float4*)(emb + (size_t)id * EMB);
    float4* dst4 = (float4*)dst;
    dst4[threadIdx.x] = src4[threadIdx.x];
}

// ---------------- gi0 as tiled GEMM, batched over {enc,dec}: out = e @ W.T + b ----------------
__global__ __launch_bounds__(256) void gi_gemm_kernel(const float* __restrict__ Ae, const float* __restrict__ We,
                                                      const float* __restrict__ be, float* __restrict__ oe,
                                                      const float* __restrict__ Ad, const float* __restrict__ Wd,
                                                      const float* __restrict__ bd, float* __restrict__ od) {
    __shared__ float As[64][64 + 1];
    __shared__ float Bs[64][64 + 1];
    const float* A = blockIdx.y ? Ad : Ae;
    const float* W = blockIdx.y ? Wd : We;
    const float* bias = blockIdx.y ? bd : be;
    float* out = blockIdx.y ? od : oe;
    int n0 = blockIdx.x * 64;
    int tid = threadIdx.x;
    int tn = tid & 15, tm = tid >> 4;
    float acc[4][4] = {};
    for (int k0 = 0; k0 < EMB; k0 += 64) {
        for (int i = tid; i < 64 * 16; i += 256) {
            int m = i >> 4, kq = i & 15;
            float4 v = *(const float4*)(A + (size_t)m * EMB + k0 + kq * 4);
            As[kq * 4 + 0][m] = v.x; As[kq * 4 + 1][m] = v.y;
            As[kq * 4 + 2][m] = v.z; As[kq * 4 + 3][m] = v.w;
        }
        for (int i = tid; i < 64 * 16; i += 256) {
            int n = i >> 4, kq = i & 15;
            float4 v = *(const float4*)(W + (size_t)(n0 + n) * EMB + k0 + kq * 4);
            Bs[kq * 4 + 0][n] = v.x; Bs[kq * 4 + 1][n] = v.y;
            Bs[kq * 4 + 2][n] = v.z; Bs[kq * 4 + 3][n] = v.w;
        }
        __syncthreads();
        #pragma unroll 8
        for (int k = 0; k < 64; ++k) {
            float a[4], b[4];
            #pragma unroll
            for (int i = 0; i < 4; ++i) a[i] = As[k][tm * 4 + i];
            #pragma unroll
            for (int j = 0; j < 4; ++j) b[j] = Bs[k][tn * 4 + j];
            #pragma unroll
            for (int i = 0; i < 4; ++i)
                #pragma unroll
                for (int j = 0; j < 4; ++j) acc[i][j] += a[i] * b[j];
        }
        __syncthreads();
    }
    #pragma unroll
    for (int i = 0; i < 4; ++i) {
        int m = tm * 4 + i;
        #pragma unroll
        for (int j = 0; j < 4; ++j) {
            int r = n0 + tn * 4 + j;
            out[(size_t)m * H3 + r] = acc[i][j] + bias[r];
        }
    }
}

// ================= persistent recurrence kernel (v7: barrier-free tagged dataflow) =================
// 192 blocks x 1024 threads. Blocks 0..63 = A (layer0): wave w -> j = bid*16+w, 3 gate rows
// in 24 packed VGPRs. Blocks 64..191 = B (layer1): j = (bid-64)*8+(w>>1); part = w&1.
// h values flow through write-once (value,tag) 8B slots: h0hist[p][j] = H0[p], h1hist[p][j]
// = H1[p]. Consumers poll their own slot (relaxed agent atomic load) until tag != 0 —
// no grid barrier, no counters, no fences. A runs phases 0..127, B runs 1..128, each at
// its own data-driven pace.
struct PArgs {
    const unsigned short *encWhh0, *encWih1, *encWhh1;
    const unsigned short *decWhh0, *decWih1, *decWhh1;
    const float *gi_enc0, *gi_dec0;
    const float *enc_bhh0, *dec_bhh0;
    const float *enc_bih1, *enc_bhh1, *dec_bih1, *dec_bhh1;
    ull *h0hist, *h1hist;
    float *states;
};

__device__ __forceinline__ void loadw24(const unsigned short* __restrict__ m,
                                        int j, int lane,
                                        u32x8& w0, u32x8& w1, u32x8& w2) {
    size_t b0 = (size_t)j * H + lane;
    size_t b1 = (size_t)(H + j) * H + lane;
    size_t b2 = (size_t)(2 * H + j) * H + lane;
    #pragma unroll
    for (int q = 0; q < 8; ++q) {
        w0[q] = (unsigned)m[b0 + 128 * q] | ((unsigned)m[b0 + 128 * q + 64] << 16);
        w1[q] = (unsigned)m[b1 + 128 * q] | ((unsigned)m[b1 + 128 * q + 64] << 16);
        w2[q] = (unsigned)m[b2 + 128 * q] | ((unsigned)m[b2 + 128 * q + 64] << 16);
    }
}

__global__ __launch_bounds__(1024, 4) void persist_kernel(PArgs a) {
    __shared__ __align__(16) float xh0[H];
    __shared__ __align__(16) float xh1[H];
    __shared__ float sred[64];
    const int tid = threadIdx.x;
    const int w = tid >> 6, lane = tid & 63;
    const int bid = blockIdx.x;

    if (bid < 64) {
        // ================= A: layer0, phases 0..127 =================
        const int j = bid * 16 + w;
        u32x8 w0, w1, w2;
        loadw24(a.encWhh0, j, lane, w0, w1, w2);
        float b0 = 0.f, b1 = 0.f, b2 = 0.f, g0 = 0.f, g1 = 0.f, g2 = 0.f;
        if (lane == 0) {
            b0 = a.enc_bhh0[j]; b1 = a.enc_bhh0[H + j]; b2 = a.enc_bhh0[2 * H + j];
            g0 = a.gi_enc0[j];  g1 = a.gi_enc0[H + j];  g2 = a.gi_enc0[2 * H + j];
        }
        for (int p = 0; p < 128; ++p) {
            // poll & stage H0[p]
            {
                const ull* src = a.h0hist + (size_t)p * 1024 + tid;
                ull v = __hip_atomic_load(src, __ATOMIC_RELAXED, __HIP_MEMORY_SCOPE_AGENT);
                while (!(v >> 32)) {
                    __builtin_amdgcn_s_sleep(1);
                    v = __hip_atomic_load(src, __ATOMIC_RELAXED, __HIP_MEMORY_SCOPE_AGENT);
                }
                xh0[tid] = __uint_as_float((unsigned)v);
            }
            __syncthreads();
            float s0 = 0.f, s1 = 0.f, s2 = 0.f;
            #pragma unroll
            for (int q = 0; q < 8; ++q) {
                float x0 = xh0[lane + 128 * q];
                float x1 = xh0[lane + 128 * q + 64];
                s0 += lof(w0[q]) * x0 + hif(w0[q]) * x1;
                s1 += lof(w1[q]) * x0 + hif(w1[q]) * x1;
                s2 += lof(w2[q]) * x0 + hif(w2[q]) * x1;
            }
            #pragma unroll
            for (int m = 1; m < 64; m <<= 1) {
                s0 += __shfl_xor(s0, m);
                s1 += __shfl_xor(s1, m);
                s2 += __shfl_xor(s2, m);
            }
            if (lane == 0) {
                float r = sigmoidf_(g0 + s0 + b0);
                float z = sigmoidf_(g1 + s1 + b1);
                float n = tanhf(g2 + r * (s2 + b2));
                float hn = (1.f - z) * n + z * xh0[j];
                __hip_atomic_store(a.h0hist + (size_t)(p + 1) * 1024 + j, packh(hn),
                                   __ATOMIC_RELAXED, __HIP_MEMORY_SCOPE_AGENT);
                if (p >= 64) a.states[(size_t)(p - 64) * 2048 + j] = hn;
                if (p < 127) {
                    const float* gn = (p + 1 < 64) ? (a.gi_enc0 + (size_t)(p + 1) * H3)
                                                   : (a.gi_dec0 + (size_t)(p + 1 - 64) * H3);
                    g0 = gn[j]; g1 = gn[H + j]; g2 = gn[2 * H + j];
                }
            }
            if (p == 63) {
                loadw24(a.decWhh0, j, lane, w0, w1, w2);
                if (lane == 0) { b0 = a.dec_bhh0[j]; b1 = a.dec_bhh0[H + j]; b2 = a.dec_bhh0[2 * H + j]; }
            }
            __syncthreads();   // xh0 stable until all waves finish this phase
        }
    } else {
        // ================= B: layer1, phases 1..128 =================
        const int bb = bid - 64;
        const int j = bb * 8 + (w >> 1);
        const int part = w & 1;   // 0: Wih1 rows (input = h0), 1: Whh1 rows (input = h1)
        u32x8 w0, w1, w2;
        loadw24(part == 0 ? a.encWih1 : a.encWhh1, j, lane, w0, w1, w2);
        float b0 = 0.f, b1 = 0.f, b2 = 0.f, b3 = 0.f, b4 = 0.f, b5 = 0.f;
        if (tid < 8) {
            int jg = bb * 8 + tid;
            b0 = a.enc_bih1[jg]; b1 = a.enc_bih1[H + jg]; b2 = a.enc_bih1[2 * H + jg];
            b3 = a.enc_bhh1[jg]; b4 = a.enc_bhh1[H + jg]; b5 = a.enc_bhh1[2 * H + jg];
        }
        for (int p = 1; p <= 128; ++p) {
            // poll & stage H0[p] and H1[p-1]
            {
                const ull* s0p = a.h0hist + (size_t)p * 1024 + tid;
                const ull* s1p = a.h1hist + (size_t)(p - 1) * 1024 + tid;
                ull v0 = __hip_atomic_load(s0p, __ATOMIC_RELAXED, __HIP_MEMORY_SCOPE_AGENT);
                ull v1 = __hip_atomic_load(s1p, __ATOMIC_RELAXED, __HIP_MEMORY_SCOPE_AGENT);
                while (!(v0 >> 32) || !(v1 >> 32)) {
                    __builtin_amdgcn_s_sleep(1);
                    if (!(v0 >> 32)) v0 = __hip_atomic_load(s0p, __ATOMIC_RELAXED, __HIP_MEMORY_SCOPE_AGENT);
                    if (!(v1 >> 32)) v1 = __hip_atomic_load(s1p, __ATOMIC_RELAXED, __HIP_MEMORY_SCOPE_AGENT);
                }
                xh0[tid] = __uint_as_float((unsigned)v0);
                xh1[tid] = __uint_as_float((unsigned)v1);
            }
            __syncthreads();
            {
                const float* x = (part == 0) ? xh0 : xh1;
                float s0 = 0.f, s1 = 0.f, s2 = 0.f;
                #pragma unroll
                for (int q = 0; q < 8; ++q) {
                    float x0 = x[lane + 128 * q];
                    float x1 = x[lane + 128 * q + 64];
                    s0 += lof(w0[q]) * x0 + hif(w0[q]) * x1;
                    s1 += lof(w1[q]) * x0 + hif(w1[q]) * x1;
                    s2 += lof(w2[q]) * x0 + hif(w2[q]) * x1;
                }
                #pragma unroll
                for (int m = 1; m < 64; m <<= 1) {
                    s0 += __shfl_xor(s0, m);
                    s1 += __shfl_xor(s1, m);
                    s2 += __shfl_xor(s2, m);
                }
                if (lane == 0) {
                    int slot = (w >> 1) * 8 + part * 4;
                    sred[slot + 0] = s0; sred[slot + 1] = s1; sred[slot + 2] = s2;
                }
            }
            __syncthreads();
            if (tid < 8) {
                int jg = bb * 8 + tid;
                float si0 = sred[tid * 8 + 0], si1 = sred[tid * 8 + 1], si2 = sred[tid * 8 + 2];
                float sh0 = sred[tid * 8 + 4], sh1 = sred[tid * 8 + 5], sh2 = sred[tid * 8 + 6];
                float r = sigmoidf_(si0 + b0 + sh0 + b3);
                float z = sigmoidf_(si1 + b1 + sh1 + b4);
                float n = tanhf(si2 + b2 + r * (sh2 + b5));
                float hn = (1.f - z) * n + z * xh1[jg];
                __hip_atomic_store(a.h1hist + (size_t)p * 1024 + jg, packh(hn),
                                   __ATOMIC_RELAXED, __HIP_MEMORY_SCOPE_AGENT);
                if (p >= 65) a.states[(size_t)(p - 65) * 2048 + H + jg] = hn;
            }
            if (p == 64) {
                loadw24(part == 0 ? a.decWih1 : a.decWhh1, j, lane, w0, w1, w2);
                if (tid < 8) {
                    int jg = bb * 8 + tid;
                    b0 = a.dec_bih1[jg]; b1 = a.dec_bih1[H + jg]; b2 = a.dec_bih1[2 * H + jg];
                    b3 = a.dec_bhh1[jg]; b4 = a.dec_bhh1[H + jg]; b5 = a.dec_bhh1[2 * H + jg];
                }
            }
            __syncthreads();
        }
    }
}

// ---------------- fallback per-phase kernel (only if cooperative launch fails) ----------------
template<int BF>
__global__ __launch_bounds__(384) void phase_kernel(
    const float* __restrict__ giA, const void* __restrict__ WhhA, const float* __restrict__ bhhA,
    const float* __restrict__ h0r, float* __restrict__ h0w, float* __restrict__ statesA, int hasA,
    const void* __restrict__ WihB, const float* __restrict__ bihB,
    const void* __restrict__ WhhB, const float* __restrict__ bhhB,
    const float* __restrict__ h1r, float* __restrict__ h1w, float* __restrict__ statesB, int hasB) {
    __shared__ float sred[8];
    int bid = blockIdx.x;
    int tid = threadIdx.x;
    int w = tid >> 6, lane = tid & 63;
    auto dotf = [&](const void* Wp, size_t roff, const float* x) -> float {
        float s = 0.f;
        if (BF) {
            const unsigned short* wrow = (const unsigned short*)Wp + roff;
            #pragma unroll
            for (int i = 0; i < 2; ++i) {
                int k = lane * 8 + i * 512;
                us8 wv = *(const us8*)(wrow + k);
                float4 x0 = *(const float4*)(x + k);
                float4 x1 = *(const float4*)(x + k + 4);
                s += bf2f(wv[0]) * x0.x + bf2f(wv[1]) * x0.y + bf2f(wv[2]) * x0.z + bf2f(wv[3]) * x0.w
                   + bf2f(wv[4]) * x1.x + bf2f(wv[5]) * x1.y + bf2f(wv[6]) * x1.z + bf2f(wv[7]) * x1.w;
            }
        } else {
            const float* wrow = (const float*)Wp + roff;
            #pragma unroll
            for (int i = 0; i < 4; ++i) {
                int k = lane * 4 + i * 256;
                float4 wv = *(const float4*)(wrow + k);
                float4 xv = *(const float4*)(x + k);
                s += wv.x * xv.x + wv.y * xv.y + wv.z * xv.z + wv.w * xv.w;
            }
        }
        return s;
    };
    if (bid < 512) {
        if (!hasA) return;
        int tt = w / 3, g = w - tt * 3;
        int jj = bid * 2 + tt;
        float s = dotf(WhhA, (size_t)(g * H + jj) * H, h0r);
        #pragma unroll
        for (int m = 1; m < 64; m <<= 1) s += __shfl_xor(s, m);
        if (lane == 0) sred[w] = s;
        __syncthreads();
        if (tid < 2) {
            int j2 = bid * 2 + tid;
            float s0 = sred[tid * 3], s1 = sred[tid * 3 + 1], s2 = sred[tid * 3 + 2];
            float r = sigmoidf_(giA[j2] + s0 + bhhA[j2]);
            float z = sigmoidf_(giA[H + j2] + s1 + bhhA[H + j2]);
            float n = tanhf(giA[2 * H + j2] + r * (s2 + bhhA[2 * H + j2]));
            float hn = (1.f - z) * n + z * h0r[j2];
            h0w[j2] = hn;
            if (statesA) statesA[j2] = hn;
        }
    } else {
        if (!hasB) return;
        int j = bid - 512;
        int hh = (w >= 3);
        int g = w - hh * 3;
        float s = dotf(hh ? WhhB : WihB, (size_t)(g * H + j) * H, hh ? h1r : h0r);
        #pragma unroll
        for (int m = 1; m < 64; m <<= 1) s += __shfl_xor(s, m);
        if (lane == 0) sred[w] = s;
        __syncthreads();
        if (tid == 0) {
            float r = sigmoidf_(sred[0] + bihB[j] + sred[3] + bhhB[j]);
            float z = sigmoidf_(sred[1] + bihB[H + j] + sred[4] + bhhB[H + j]);
            float n = tanhf(sred[2] + bihB[2 * H + j] + r * (sred[5] + bhhB[2 * H + j]));
            float hn = (1.f - z) * n + z * h1r[j];
            h1w[j] = hn;
            if (statesB) statesB[j] = hn;
        }
    }
}

// ---------------- scores GEMM, split-K (f32 weights) ----------------
#define SN 64
#define SK 64
__global__ __launch_bounds__(256) void scores_kernel(const float* __restrict__ states,
                                                     const float* __restrict__ W,
                                                     const float* __restrict__ bias,
                                                     float* __restrict__ dst, int kc_count) {
    __shared__ float As[SK][64 + 1];
    __shared__ float Bs[SK][SN + 1];
    int n0 = blockIdx.x * SN;
    int kc = blockIdx.y;
    int klen = H / kc_count;
    int kbeg = kc * klen;
    int tid = threadIdx.x;
    int tn = tid & 15, tm = tid >> 4;
    float acc[4][4] = {};
    for (int k0 = kbeg; k0 < kbeg + klen; k0 += SK) {
        for (int i = tid; i < 64 * (SK / 4); i += 256) {
            int m = i >> 4;
            int kq = i & 15;
            float4 v = *(const float4*)(states + (size_t)m * 2048 + H + k0 + kq * 4);
            As[kq * 4 + 0][m] = v.x; As[kq * 4 + 1][m] = v.y;
            As[kq * 4 + 2][m] = v.z; As[kq * 4 + 3][m] = v.w;
        }
        for (int i = tid; i < SN * (SK / 4); i += 256) {
            int n = i >> 4;
            int kq = i & 15;
            int r = n0 + n;
            float4 v = make_float4(0.f, 0.f, 0.f, 0.f);
            if (r < V) v = *(const float4*)(W + (size_t)r * H + k0 + kq * 4);
            Bs[kq * 4 + 0][n] = v.x; Bs[kq * 4 + 1][n] = v.y;
            Bs[kq * 4 + 2][n] = v.z; Bs[kq * 4 + 3][n] = v.w;
        }
        __syncthreads();
        #pragma unroll 8
        for (int k = 0; k < SK; ++k) {
            float a[4], b[4];
            #pragma unroll
            for (int i = 0; i < 4; ++i) a[i] = As[k][tm * 4 + i];
            #pragma unroll
            for (int j = 0; j < 4; ++j) b[j] = Bs[k][tn * 4 + j];
            #pragma unroll
            for (int i = 0; i < 4; ++i)
                #pragma unroll
                for (int j = 0; j < 4; ++j) acc[i][j] += a[i] * b[j];
        }
        __syncthreads();
    }
    if (kc_count == 1) {
        #pragma unroll
        for (int i = 0; i < 4; ++i) {
            int m = tm * 4 + i;
            #pragma unroll
            for (int j = 0; j < 4; ++j) {
                int r = n0 + tn * 4 + j;
                if (r < V) dst[(size_t)m * V + r] = acc[i][j] + bias[r];
            }
        }
    } else {
        #pragma unroll
        for (int i = 0; i < 4; ++i) {
            int m = tm * 4 + i;
            #pragma unroll
            for (int j = 0; j < 4; ++j) {
                int r = n0 + tn * 4 + j;
                dst[(size_t)(kc * 64 + m) * NPAD + r] = acc[i][j];
            }
        }
    }
}

__global__ __launch_bounds__(256) void reduce_scores_kernel(const float* __restrict__ part,
                                                            const float* __restrict__ bias,
                                                            float* __restrict__ out, int kc_count) {
    int e = blockIdx.x * 256 + threadIdx.x;
    if (e >= 64 * V) return;
    int m = e / V, r = e - m * V;
    float s = bias[r];
    for (int kc = 0; kc < kc_count; ++kc)
        s += part[(size_t)(kc * 64 + m) * NPAD + r];
    out[(size_t)m * V + r] = s;
}

extern "C" void kernel_launch(void* const* d_in, const int* in_sizes, int n_in,
                              void* d_out, int out_size, void* d_ws, size_t ws_size,
                              hipStream_t stream) {
    const int*   char_seq  = (const int*)d_in[0];
    const float* enc_state = (const float*)d_in[1];
    const int*   sos       = (const int*)d_in[2];
    const int*   tgt       = (const int*)d_in[5];
    const float* emb       = (const float*)d_in[6];
    const float* enc_Wih0  = (const float*)d_in[7];
    const float* enc_Whh0  = (const float*)d_in[8];
    const float* enc_bih0  = (const float*)d_in[9];
    const float* enc_bhh0  = (const float*)d_in[10];
    const float* enc_Wih1  = (const float*)d_in[11];
    const float* enc_Whh1  = (const float*)d_in[12];
    const float* enc_bih1  = (const float*)d_in[13];
    const float* enc_bhh1  = (const float*)d_in[14];
    const float* dec_Wih0  = (const float*)d_in[15];
    const float* dec_Whh0  = (const float*)d_in[16];
    const float* dec_bih0  = (const float*)d_in[17];
    const float* dec_bhh0  = (const float*)d_in[18];
    const float* dec_Wih1  = (const float*)d_in[19];
    const float* dec_Whh1  = (const float*)d_in[20];
    const float* dec_bih1  = (const float*)d_in[21];
    const float* dec_bhh1  = (const float*)d_in[22];
    const float* out_W     = (const float*)d_in[23];
    const float* out_b     = (const float*)d_in[24];

    float* ws = (float*)d_ws;
    float* e_enc   = ws;                       // 64*512
    float* e_dec   = e_enc + SEQ * EMB;        // 64*512
    float* gi_enc0 = e_dec + SEQ * EMB;        // 64*3072
    float* gi_dec0 = gi_enc0 + SEQ * H3;       // 64*3072
    ull*   h0hist  = (ull*)(gi_dec0 + SEQ * H3);        // NPH*1024 ull
    ull*   h1hist  = h0hist + (size_t)NPH * 1024;       // NPH*1024 ull
    float* h0buf   = (float*)(h1hist + (size_t)NPH * 1024);  // 2*1024 (fallback)
    float* h1buf   = h0buf + 2 * H;                          // 2*1024 (fallback)
    float* cur     = h1buf + 2 * H;
    size_t base = (size_t)(cur - ws);
    size_t avail = ws_size / 4 > base ? ws_size / 4 - base : 0;

    const size_t REC_ELEMS = (size_t)H3 * H;   // per matrix
    const size_t REC_SLOTS = REC_ELEMS / 2;    // float-slots per bf16 matrix

    int bf_rec = (avail >= 6 * REC_SLOTS);
    unsigned short* wbf0 = nullptr;
    if (bf_rec) { wbf0 = (unsigned short*)cur; cur += 6 * REC_SLOTS; avail -= 6 * REC_SLOTS; }
    int KC = 1;
    if (avail >= (size_t)8 * 64 * NPAD) KC = 8;
    else if (avail >= (size_t)4 * 64 * NPAD) KC = 4;
    else if (avail >= (size_t)2 * 64 * NPAD) KC = 2;
    float* partials = cur;

    float* scores = (float*)d_out;             // 64*10000
    float* states = scores + SEQ * V;          // 64*2048

    if (bf_rec) {
        CvtArgs c;
        c.src[0] = enc_Whh0; c.src[1] = enc_Wih1; c.src[2] = enc_Whh1;
        c.src[3] = dec_Whh0; c.src[4] = dec_Wih1; c.src[5] = dec_Whh1;
        c.dst0 = wbf0;
        f2bf6_kernel<<<dim3((unsigned)(REC_ELEMS / 2048), 6), 256, 0, stream>>>(c);
    }
    init2_kernel<<<(NPH * 1024 + 255) / 256, 256, 0, stream>>>(enc_state, h0hist, h1hist, h0buf, h1buf);
    embed_kernel<<<128, 128, 0, stream>>>(char_seq, sos, tgt, emb, e_enc, e_dec);
    gi_gemm_kernel<<<dim3(H3 / 64, 2), 256, 0, stream>>>(e_enc, enc_Wih0, enc_bih0, gi_enc0,
                                                         e_dec, dec_Wih0, dec_bih0, gi_dec0);

    bool done = false;
    if (bf_rec) {
        PArgs pa;
        pa.encWhh0 = wbf0;
        pa.encWih1 = wbf0 + REC_ELEMS;
        pa.encWhh1 = wbf0 + 2 * REC_ELEMS;
        pa.decWhh0 = wbf0 + 3 * REC_ELEMS;
        pa.decWih1 = wbf0 + 4 * REC_ELEMS;
        pa.decWhh1 = wbf0 + 5 * REC_ELEMS;
        pa.gi_enc0 = gi_enc0; pa.gi_dec0 = gi_dec0;
        pa.enc_bhh0 = enc_bhh0; pa.dec_bhh0 = dec_bhh0;
        pa.enc_bih1 = enc_bih1; pa.enc_bhh1 = enc_bhh1;
        pa.dec_bih1 = dec_bih1; pa.dec_bhh1 = dec_bhh1;
        pa.h0hist = h0hist; pa.h1hist = h1hist; pa.states = states;
        void* kparams[] = { (void*)&pa };
        hipError_t err = hipLaunchCooperativeKernel((const void*)persist_kernel,
                                                    dim3(192), dim3(1024), kparams, 0, stream);
        done = (err == hipSuccess);
    }

    if (!done) {
        for (int p = 0; p <= 128; ++p) {
            int hasA = (p <= 127);
            int hasB = (p >= 1);
            const float* giA = nullptr; const void* WhhA = nullptr; const float* bhhA = nullptr;
            float* statesA = nullptr;
            if (hasA) {
                if (p < 64) {
                    giA = gi_enc0 + (size_t)p * H3; bhhA = enc_bhh0;
                    WhhA = bf_rec ? (const void*)wbf0 : (const void*)enc_Whh0;
                } else {
                    int t = p - 64;
                    giA = gi_dec0 + (size_t)t * H3; bhhA = dec_bhh0;
                    WhhA = bf_rec ? (const void*)(wbf0 + 3 * REC_ELEMS) : (const void*)dec_Whh0;
                    statesA = states + (size_t)t * 2048;
                }
            }
            const void *WihB = nullptr, *WhhB = nullptr;
            const float *bihB = nullptr, *bhhB = nullptr;
            float* statesB = nullptr;
            if (hasB) {
                if (p <= 64) {
                    bihB = enc_bih1; bhhB = enc_bhh1;
                    WihB = bf_rec ? (const void*)(wbf0 + REC_ELEMS) : (const void*)enc_Wih1;
                    WhhB = bf_rec ? (const void*)(wbf0 + 2 * REC_ELEMS) : (const void*)enc_Whh1;
                } else {
                    int t = p - 65;
                    bihB = dec_bih1; bhhB = dec_bhh1;
                    WihB = bf_rec ? (const void*)(wbf0 + 4 * REC_ELEMS) : (const void*)dec_Wih1;
                    WhhB = bf_rec ? (const void*)(wbf0 + 5 * REC_ELEMS) : (const void*)dec_Whh1;
                    statesB = states + (size_t)t * 2048 + H;
                }
            }
            float* h0r = h0buf + (p & 1) * H;
            float* h0w = h0buf + ((p + 1) & 1) * H;
            float* h1r = h1buf + (p & 1) * H;
            float* h1w = h1buf + ((p + 1) & 1) * H;
            if (bf_rec)
                phase_kernel<1><<<1536, 384, 0, stream>>>(giA, WhhA, bhhA, h0r, h0w, statesA, hasA,
                                                          WihB, bihB, WhhB, bhhB, h1r, h1w, statesB, hasB);
            else
                phase_kernel<0><<<1536, 384, 0, stream>>>(giA, WhhA, bhhA, h0r, h0w, statesA, hasA,
                                                          WihB, bihB, WhhB, bhhB, h1r, h1w, statesB, hasB);
        }
    }

    if (KC == 1) {
        scores_kernel<<<dim3((V + SN - 1) / SN, 1), 256, 0, stream>>>(states, out_W, out_b, scores, 1);
    } else {
        scores_kernel<<<dim3((V + SN - 1) / SN, KC), 256, 0, stream>>>(states, out_W, out_b, partials, KC);
        reduce_scores_kernel<<<(64 * V + 255) / 256, 256, 0, stream>>>(partials, out_b, scores, KC);
    }
}